// Round 5
// baseline (207.738 us; speedup 1.0000x reference)
//
#include <hip/hip_runtime.h>

// sparsegen-lin, lam = 0.5  =>  p = sparsemax(2*x) along rows of length 2048.
// tau solves sum(max(z - tau, 0)) = 1; 5 bisection steps bracket it from
// max(z), then 2 Michelot passes make it (near-)exact.
//
// R4 finding: the read stream runs at only ~4.4 TB/s because each wave's
// serial reduction (~78 dependent shuffles) leaves the memory pipe idle
// between row loads (convoy effect). Fix: register double-buffer — each
// wave prefetches row r+1's 8 float4 before computing row r, so loads for
// the next row are always in flight behind the shuffle chains.

static constexpr float SCALE = 2.0f;   // 1/(1-lam), lam = 0.5
static constexpr int ROWLEN = 2048;
static constexpr int BLOCKS = 2048;    // x4 waves = 8192 waves, 8 rows/wave

using vfloat4 = __attribute__((ext_vector_type(4))) float;

__device__ __forceinline__ void load_row(const float* __restrict__ in,
                                         long long row, int lane,
                                         vfloat4 (&z)[8])
{
    const float* rp = in + row * (long long)ROWLEN;
#pragma unroll
    for (int i = 0; i < 8; ++i) {
        vfloat4 v = *reinterpret_cast<const vfloat4*>(rp + i * 256 + lane * 4);
        z[i] = v * SCALE;
    }
}

__device__ __forceinline__ void proc_row(float* __restrict__ out,
                                         long long row, int lane,
                                         vfloat4 (&z)[8])
{
    // Row max: 4 parallel accumulators, then 64-lane butterfly.
    float m0 = -3.4e38f, m1 = -3.4e38f, m2 = -3.4e38f, m3 = -3.4e38f;
#pragma unroll
    for (int i = 0; i < 8; ++i) {
        m0 = fmaxf(m0, z[i].x); m1 = fmaxf(m1, z[i].y);
        m2 = fmaxf(m2, z[i].z); m3 = fmaxf(m3, z[i].w);
    }
    float m = fmaxf(fmaxf(m0, m1), fmaxf(m2, m3));
#pragma unroll
    for (int off = 32; off >= 1; off >>= 1)
        m = fmaxf(m, __shfl_xor(m, off, 64));

    // 5 bisection steps; invariant lo <= tau* <= hi.
    float lo = m - 1.0f, hi = m;
#pragma unroll
    for (int it = 0; it < 5; ++it) {
        const float mid = 0.5f * (lo + hi);
        float s0 = 0.0f, s1 = 0.0f, s2 = 0.0f, s3 = 0.0f;
#pragma unroll
        for (int i = 0; i < 8; ++i) {
            s0 += fmaxf(z[i].x - mid, 0.0f);
            s1 += fmaxf(z[i].y - mid, 0.0f);
            s2 += fmaxf(z[i].z - mid, 0.0f);
            s3 += fmaxf(z[i].w - mid, 0.0f);
        }
        float s = (s0 + s1) + (s2 + s3);
#pragma unroll
        for (int off = 32; off >= 1; off >>= 1)
            s += __shfl_xor(s, off, 64);
        if (s >= 1.0f) lo = mid; else hi = mid;  // wave-uniform branch
    }

    // Two Michelot passes from t = lo <= tau*.
    float t = lo;
#pragma unroll
    for (int pass = 0; pass < 2; ++pass) {
        float s0 = 0.0f, s1 = 0.0f, s2 = 0.0f, s3 = 0.0f;
        float k0 = 0.0f, k1 = 0.0f, k2 = 0.0f, k3 = 0.0f;
#pragma unroll
        for (int i = 0; i < 8; ++i) {
            s0 += (z[i].x > t) ? z[i].x : 0.0f;  k0 += (z[i].x > t) ? 1.0f : 0.0f;
            s1 += (z[i].y > t) ? z[i].y : 0.0f;  k1 += (z[i].y > t) ? 1.0f : 0.0f;
            s2 += (z[i].z > t) ? z[i].z : 0.0f;  k2 += (z[i].z > t) ? 1.0f : 0.0f;
            s3 += (z[i].w > t) ? z[i].w : 0.0f;  k3 += (z[i].w > t) ? 1.0f : 0.0f;
        }
        float s = (s0 + s1) + (s2 + s3);
        float k = (k0 + k1) + (k2 + k3);
#pragma unroll
        for (int off = 32; off >= 1; off >>= 1) {
            s += __shfl_xor(s, off, 64);
            k += __shfl_xor(k, off, 64);
        }
        t = (s - 1.0f) / fmaxf(k, 1.0f);   // k >= 1 always
    }

    // Dense coalesced stores (nontemporal: output is never re-read).
    float* op = out + row * (long long)ROWLEN;
#pragma unroll
    for (int i = 0; i < 8; ++i) {
        vfloat4 p;
        p.x = fmaxf(z[i].x - t, 0.0f);
        p.y = fmaxf(z[i].y - t, 0.0f);
        p.z = fmaxf(z[i].z - t, 0.0f);
        p.w = fmaxf(z[i].w - t, 0.0f);
        __builtin_nontemporal_store(
            p, reinterpret_cast<vfloat4*>(op + i * 256 + lane * 4));
    }
}

__global__ __launch_bounds__(256) void sparsegen_lin_pipe_kernel(
    const float* __restrict__ in, float* __restrict__ out,
    int nrows, int nwaves)
{
    const int lane = threadIdx.x & 63;
    const long long wid =
        ((long long)blockIdx.x * blockDim.x + threadIdx.x) >> 6;
    if (wid >= nrows) return;

    const long long W = nwaves;
    vfloat4 A[8], B[8];

    long long r = wid;
    load_row(in, r, lane, A);           // prime the pipeline
    for (;;) {
        const long long r1 = r + W;
        if (r1 < nrows) {
            load_row(in, r1, lane, B);  // prefetch next row behind A's compute
            proc_row(out, r, lane, A);
            const long long r2 = r1 + W;
            if (r2 < nrows) {
                load_row(in, r2, lane, A);
                proc_row(out, r1, lane, B);
                r = r2;
            } else {
                proc_row(out, r1, lane, B);
                return;
            }
        } else {
            proc_row(out, r, lane, A);
            return;
        }
    }
}

extern "C" void kernel_launch(void* const* d_in, const int* in_sizes, int n_in,
                              void* d_out, int out_size, void* d_ws, size_t ws_size,
                              hipStream_t stream)
{
    const float* in = (const float*)d_in[0];
    float* out = (float*)d_out;
    const int total = in_sizes[0];
    const int nrows = total / ROWLEN;        // 65536 for the bench shape
    const int nwaves = BLOCKS * (256 / 64);  // 8192 waves in flight
    sparsegen_lin_pipe_kernel<<<BLOCKS, 256, 0, stream>>>(in, out, nrows, nwaves);
}

// Round 6
// 202.022 us; speedup vs baseline: 1.0283x; 1.0283x over previous
//
#include <hip/hip_runtime.h>

// sparsegen-lin, lam = 0.5  =>  p = sparsemax(2*x) along rows of length 2048.
// tau solves sum(max(z - tau, 0)) = 1; 5 bisection steps from max(z), then
// 2 Michelot passes.
//
// R6: occupancy experiment. All prior variants held >64 VGPR -> 4 waves/SIMD;
// the read stream stalled at ~4.4 TB/s because average in-flight bytes/CU
// (waves/SIMD x 8KB x latency duty) was borderline. Target <=64 VGPR via
// __launch_bounds__(256,8): 2-wide accumulators, no double-buffer, scatter
// stores. Memset pass handles the zeros at the measured 6.7 TB/s fill rate.

static constexpr float SCALE = 2.0f;   // 1/(1-lam), lam = 0.5
static constexpr int ROWLEN = 2048;
static constexpr int WPB = 4;          // waves (rows) per 256-thread block

using vfloat4 = __attribute__((ext_vector_type(4))) float;

__global__ __launch_bounds__(256, 8) void sparsegen_tau_scatter_kernel(
    const float* __restrict__ in, float* __restrict__ out, int nrows)
{
    const int wave = threadIdx.x >> 6;
    const int lane = threadIdx.x & 63;
    const long long row = (long long)blockIdx.x * WPB + wave;
    if (row >= nrows) return;

    const float* rp = in + row * (long long)ROWLEN + lane * 4;

    // 32 floats/lane, register-resident (32 VGPR — the data floor).
    vfloat4 z[8];
#pragma unroll
    for (int i = 0; i < 8; ++i) {
        vfloat4 v = __builtin_nontemporal_load(
            reinterpret_cast<const vfloat4*>(rp + i * 256));
        z[i] = v * SCALE;
    }

    // Row max: 2 accumulators (VGPR-lean), then 64-lane butterfly.
    float m0 = -3.4e38f, m1 = -3.4e38f;
#pragma unroll
    for (int i = 0; i < 8; ++i) {
        m0 = fmaxf(m0, fmaxf(z[i].x, z[i].y));
        m1 = fmaxf(m1, fmaxf(z[i].z, z[i].w));
    }
    float m = fmaxf(m0, m1);
#pragma unroll
    for (int off = 32; off >= 1; off >>= 1)
        m = fmaxf(m, __shfl_xor(m, off, 64));

    // 5 bisection steps on f(tau) = sum(max(z-tau,0)) - 1; lo <= tau* <= hi.
    float lo = m - 1.0f, hi = m;
#pragma unroll
    for (int it = 0; it < 5; ++it) {
        const float mid = 0.5f * (lo + hi);
        float s0 = 0.0f, s1 = 0.0f;
#pragma unroll
        for (int i = 0; i < 8; ++i) {
            s0 += fmaxf(z[i].x - mid, 0.0f) + fmaxf(z[i].y - mid, 0.0f);
            s1 += fmaxf(z[i].z - mid, 0.0f) + fmaxf(z[i].w - mid, 0.0f);
        }
        float s = s0 + s1;
#pragma unroll
        for (int off = 32; off >= 1; off >>= 1)
            s += __shfl_xor(s, off, 64);
        if (s >= 1.0f) lo = mid; else hi = mid;  // wave-uniform branch
    }

    // Two Michelot passes from t = lo <= tau*: S = {z > t} superset of true
    // support; t' = (sum_S z - 1)/|S| <= tau*, monotone convergent.
    float t = lo;
#pragma unroll
    for (int pass = 0; pass < 2; ++pass) {
        float s0 = 0.0f, s1 = 0.0f;
        float k0 = 0.0f, k1 = 0.0f;
#pragma unroll
        for (int i = 0; i < 8; ++i) {
            s0 += (z[i].x > t) ? z[i].x : 0.0f;  k0 += (z[i].x > t) ? 1.0f : 0.0f;
            s0 += (z[i].y > t) ? z[i].y : 0.0f;  k0 += (z[i].y > t) ? 1.0f : 0.0f;
            s1 += (z[i].z > t) ? z[i].z : 0.0f;  k1 += (z[i].z > t) ? 1.0f : 0.0f;
            s1 += (z[i].w > t) ? z[i].w : 0.0f;  k1 += (z[i].w > t) ? 1.0f : 0.0f;
        }
        float s = s0 + s1;
        float k = k0 + k1;
#pragma unroll
        for (int off = 32; off >= 1; off >>= 1) {
            s += __shfl_xor(s, off, 64);   // two independent chains overlap
            k += __shfl_xor(k, off, 64);
        }
        t = (s - 1.0f) / fmaxf(k, 1.0f);   // k >= 1 (max element is in S)
    }

    // Scatter only the support (~2-5 stores/row); out already zeroed.
    float* op = out + row * (long long)ROWLEN + lane * 4;
#pragma unroll
    for (int i = 0; i < 8; ++i) {
        if (z[i].x > t) __builtin_nontemporal_store(z[i].x - t, op + i * 256 + 0);
        if (z[i].y > t) __builtin_nontemporal_store(z[i].y - t, op + i * 256 + 1);
        if (z[i].z > t) __builtin_nontemporal_store(z[i].z - t, op + i * 256 + 2);
        if (z[i].w > t) __builtin_nontemporal_store(z[i].w - t, op + i * 256 + 3);
    }
}

extern "C" void kernel_launch(void* const* d_in, const int* in_sizes, int n_in,
                              void* d_out, int out_size, void* d_ws, size_t ws_size,
                              hipStream_t stream)
{
    const float* in = (const float*)d_in[0];
    float* out = (float*)d_out;
    const int total = in_sizes[0];
    const int nrows = total / ROWLEN;          // 65536 for the bench shape

    // Pure-write pass: zero the output at fill rate (~6.7 TB/s measured).
    hipMemsetAsync(d_out, 0, (size_t)out_size * sizeof(float), stream);

    // Pure-read pass + sparse scatter, one row per wave.
    const int blocks = (nrows + WPB - 1) / WPB;
    sparsegen_tau_scatter_kernel<<<blocks, 256, 0, stream>>>(in, out, nrows);
}